// Round 8
// baseline (306.892 us; speedup 1.0000x reference)
//
#include <hip/hip_runtime.h>
#include <hip/hip_bf16.h>

// out = data @ (mask*weight)^T + bias, via bf16 MFMA.
// Round 8: R7 geometry (dbuf-2, BK=64 as two 32-col R4-swizzled blocks,
// 4 phases/K-tile, 2 gload_lds/phase, counted vmcnt) + cross-phase REGISTER
// prefetch: each phase issues ds_reads for phase p+1 and MFMAs phase p-1's
// regs -> compiler emits counted (non-draining) lgkmcnt. No lgkm drain in loop.

#define GM 8192
#define GN 4096
#define GK 4096
#define NT (GK / 64)   // 64 K-tiles of BK=64

typedef __attribute__((ext_vector_type(8))) short short8;
typedef __attribute__((ext_vector_type(8))) short bf16x8;
typedef __attribute__((ext_vector_type(4))) float f32x4;

__device__ __forceinline__ short f2bf(float x) {
    unsigned u = __builtin_bit_cast(unsigned, x);
    u += 0x7fffu + ((u >> 16) & 1u);
    return (short)(u >> 16);
}

__device__ __forceinline__ void stage16(const short* g, short* l) {
    __builtin_amdgcn_global_load_lds(
        (const __attribute__((address_space(1))) unsigned int*)g,
        (__attribute__((address_space(3))) unsigned int*)l, 16, 0, 0);
}

// --- conversion: data f32 -> bf16 ---
__global__ void cvt_data_kernel(const float* __restrict__ in, short* __restrict__ out, long n) {
    long i0 = ((long)blockIdx.x * blockDim.x + threadIdx.x) * 8;
    long stride = (long)gridDim.x * blockDim.x * 8;
    for (long i = i0; i < n; i += stride) {
        float4 a = *(const float4*)(in + i);
        float4 b = *(const float4*)(in + i + 4);
        short8 o;
        o[0] = f2bf(a.x); o[1] = f2bf(a.y); o[2] = f2bf(a.z); o[3] = f2bf(a.w);
        o[4] = f2bf(b.x); o[5] = f2bf(b.y); o[6] = f2bf(b.z); o[7] = f2bf(b.w);
        *(short8*)(out + i) = o;
    }
}

// --- conversion: (mask * weight) f32 -> bf16 ---
__global__ void cvt_w_kernel(const float* __restrict__ w, const float* __restrict__ m,
                             short* __restrict__ out, long n) {
    long i0 = ((long)blockIdx.x * blockDim.x + threadIdx.x) * 8;
    long stride = (long)gridDim.x * blockDim.x * 8;
    for (long i = i0; i < n; i += stride) {
        float4 wa = *(const float4*)(w + i);
        float4 wb = *(const float4*)(w + i + 4);
        float4 ma = *(const float4*)(m + i);
        float4 mb = *(const float4*)(m + i + 4);
        short8 o;
        o[0] = f2bf(wa.x * ma.x); o[1] = f2bf(wa.y * ma.y);
        o[2] = f2bf(wa.z * ma.z); o[3] = f2bf(wa.w * ma.w);
        o[4] = f2bf(wb.x * mb.x); o[5] = f2bf(wb.y * mb.y);
        o[6] = f2bf(wb.z * mb.z); o[7] = f2bf(wb.w * mb.w);
        *(short8*)(out + i) = o;
    }
}

// --- fine-phase pipelined bf16 NT GEMM ---
// LDS (shorts): dbuf d at d*32768: A kb0 +0, A kb1 +8192, B kb0 +16384,
//   B kb1 +24576. Block = [256r][32c] bf16, 64B rows, R4 quarter-swizzle
//   (stored q = logical q ^ ((((row>>3)&1)<<1)|((row>>1)&1))) — measured 0-conflict.
//
// Per K-tile T, 4 phases. Phase p = { ds_reads for p+1 ; stage unit of T+1 ;
//   sched_barrier ; setprio(1) ; 16 MFMA on p-1's regs ; setprio(0) ;
//   [p0,p2: vmcnt(2) (last tile: vmcnt(0))] ; barrier }.
// Read schedule (reg sets alternate even/odd phase):
//   p0 -> A[mh1,kb0](T)          p1 -> A[mh0,kb1](T) + B[kb1](T)
//   p2 -> A[mh1,kb1](T)          p3 -> A[mh0,kb0](T+1) + B[kb0](T+1)
// Stage units of T+1: U0=A.kb0@p0, U1=B.kb0@p1, U2=A.kb1@p2, U3=B.kb1@p3.
// FIFO trace (steady): p0-end outstanding [U2(T),U3(T),U0(T+1)] -> vmcnt(2)
//   confirms U2,U3(T) for p1's reads (cross-wave safe: reads after barrier).
//   p2-end outstanding [U0,U1,U2(T+1)] -> vmcnt(2) confirms U0,U1(T+1) for p3.
// WAR per region >= 3 phases (barrier-separated). Tail: vmcnt(0) at p0/p2 of
// last tile (counted wait under-confirms there); p3 reads guarded off.
__global__ __launch_bounds__(512, 2) void gemm_8w(const short* __restrict__ A,
                                                  const short* __restrict__ B,
                                                  const float* __restrict__ bias,
                                                  float* __restrict__ C) {
    __shared__ short lds[65536];  // 128 KB

    const int tid  = threadIdx.x;
    const int lane = tid & 63;
    const int wid  = tid >> 6;   // 0..7
    const int wr   = wid >> 2;   // 0..1  (wave row: 128 rows)
    const int wc   = wid & 3;    // 0..3  (wave col: 64 cols)

    // XCD-aware bijective swizzle: nwg = 512, % 8 == 0
    const int bid  = blockIdx.x;
    const int swz  = (bid & 7) * 64 + (bid >> 3);
    const int brow = (swz >> 4) << 8;   // 32 M-tiles
    const int bcol = (swz & 15) << 8;   // 16 N-tiles

    // ---- staging constants (pre-swizzled global source; linear LDS dest) ----
    const int trow = tid >> 2;          // row within 128-row chunk
    const int qlog = (tid & 3) ^ ((((trow >> 3) & 1) << 1) | ((trow >> 1) & 1));

    // ---- fragment-read constants (R4's swizzled read) ----
    const int l15 = lane & 15;
    const int q   = lane >> 4;
    const int qx  = (((l15 >> 3) & 1) << 1) | ((l15 >> 1) & 1);
    const int foff = l15 * 32 + ((q ^ qx) << 3);   // shorts, within block
    const int aW = wr * 4096;                       // + dbuf + kb*8192 + m*512
    const int bW = wc * 2048;                       // + dbuf + 16384 + kb*8192 + n*512

    f32x4 acc[8][4] = {};
    bf16x8 af0[4], af1[4], bf0[4], bf1[4];  // af: even/odd-phase sets; bf: kb0/kb1

    auto stA = [&](int kb, int sb, size_t kcol) {
        #pragma unroll
        for (int j = 0; j < 2; ++j)
            stage16(A + (size_t)(brow + j * 128 + trow) * GK + kcol + kb * 32 + qlog * 8,
                    &lds[sb + kb * 8192 + j * 4096 + wid * 512]);
    };
    auto stB = [&](int kb, int sb, size_t kcol) {
        #pragma unroll
        for (int j = 0; j < 2; ++j)
            stage16(B + (size_t)(bcol + j * 128 + trow) * GK + kcol + kb * 32 + qlog * 8,
                    &lds[sb + 16384 + kb * 8192 + j * 4096 + wid * 512]);
    };

    // ---- prologue: stage tile 0 (U0..U3); confirm U0,U1; initial reads ----
    stA(0, 0, 0); stB(0, 0, 0); stA(1, 0, 0); stB(1, 0, 0);
    asm volatile("s_waitcnt vmcnt(4)" ::: "memory");   // U0,U1(0) landed
    __builtin_amdgcn_s_barrier();
    asm volatile("" ::: "memory");
    #pragma unroll
    for (int m = 0; m < 4; ++m) af0[m] = *(const bf16x8*)&lds[aW + m * 512 + foff];
    #pragma unroll
    for (int n = 0; n < 4; ++n) bf0[n] = *(const bf16x8*)&lds[16384 + bW + n * 512 + foff];

#define PHASE(RDSTMT, STGSTMT, AFSET, BFSET, MH, VMSTMT)                           \
  {                                                                                 \
    RDSTMT;                                                                         \
    STGSTMT;                                                                        \
    __builtin_amdgcn_sched_barrier(0);                                              \
    __builtin_amdgcn_s_setprio(1);                                                  \
    _Pragma("unroll")                                                               \
    for (int m = 0; m < 4; ++m)                                                     \
      _Pragma("unroll")                                                             \
      for (int n = 0; n < 4; ++n)                                                   \
        acc[(MH) * 4 + m][n] = __builtin_amdgcn_mfma_f32_16x16x32_bf16(             \
            AFSET[m], BFSET[n], acc[(MH) * 4 + m][n], 0, 0, 0);                     \
    __builtin_amdgcn_s_setprio(0);                                                  \
    VMSTMT;                                                                         \
    __builtin_amdgcn_s_barrier();                                                   \
    asm volatile("" ::: "memory");                                                  \
  }

    for (int T = 0; T < NT; ++T) {
        const int cb = (T & 1) << 15;        // compute dbuf base (shorts)
        const int sb = 32768 - cb;           // stage dbuf base
        const size_t kn = (size_t)(T + 1) * 64;
        const bool st = (T + 1 < NT);

        // p0: MFMA(af0 x bf0, mh0,kb0) ; read af1 <- A[mh1,kb0](T) ; stage U0
        PHASE(
            { _Pragma("unroll")
              for (int m = 0; m < 4; ++m)
                  af1[m] = *(const bf16x8*)&lds[cb + aW + (4 + m) * 512 + foff]; },
            if (st) stA(0, sb, kn),
            af0, bf0, 0,
            if (st) { asm volatile("s_waitcnt vmcnt(2)" ::: "memory"); }
            else    { asm volatile("s_waitcnt vmcnt(0)" ::: "memory"); })

        // p1: MFMA(af1 x bf0, mh1,kb0) ; read af0 <- A[mh0,kb1](T), bf1 <- B[kb1](T) ; stage U1
        PHASE(
            { _Pragma("unroll")
              for (int m = 0; m < 4; ++m)
                  af0[m] = *(const bf16x8*)&lds[cb + 8192 + aW + m * 512 + foff];
              _Pragma("unroll")
              for (int n = 0; n < 4; ++n)
                  bf1[n] = *(const bf16x8*)&lds[cb + 16384 + 8192 + bW + n * 512 + foff]; },
            if (st) stB(0, sb, kn),
            af1, bf0, 1, )

        // p2: MFMA(af0 x bf1, mh0,kb1) ; read af1 <- A[mh1,kb1](T) ; stage U2
        PHASE(
            { _Pragma("unroll")
              for (int m = 0; m < 4; ++m)
                  af1[m] = *(const bf16x8*)&lds[cb + 8192 + aW + (4 + m) * 512 + foff]; },
            if (st) stA(1, sb, kn),
            af0, bf1, 0,
            if (st) { asm volatile("s_waitcnt vmcnt(2)" ::: "memory"); }
            else    { asm volatile("s_waitcnt vmcnt(0)" ::: "memory"); })

        // p3: MFMA(af1 x bf1, mh1,kb1) ; read af0 <- A[mh0,kb0](T+1), bf0 <- B[kb0](T+1) ; stage U3
        PHASE(
            if (st) {
              _Pragma("unroll")
              for (int m = 0; m < 4; ++m)
                  af0[m] = *(const bf16x8*)&lds[sb + aW + m * 512 + foff];
              _Pragma("unroll")
              for (int n = 0; n < 4; ++n)
                  bf0[n] = *(const bf16x8*)&lds[sb + 16384 + bW + n * 512 + foff];
            },
            if (st) stB(1, sb, kn),
            af1, bf1, 1, )
    }
#undef PHASE

    // ---- epilogue: C/D layout col = lane&15, row = (lane>>4)*4 + r ----
    #pragma unroll
    for (int n = 0; n < 4; ++n) {
        const int col = bcol + wc * 64 + n * 16 + l15;
        const float bv = bias[col];
        #pragma unroll
        for (int m = 0; m < 8; ++m) {
            const int rowb = brow + wr * 128 + m * 16 + (q << 2);
            #pragma unroll
            for (int r = 0; r < 4; ++r)
                C[(size_t)(rowb + r) * GN + col] = acc[m][n][r] + bv;
        }
    }
}

extern "C" void kernel_launch(void* const* d_in, const int* in_sizes, int n_in,
                              void* d_out, int out_size, void* d_ws, size_t ws_size,
                              hipStream_t stream) {
    const float* data   = (const float*)d_in[0];  // [8192,4096]
    const float* weight = (const float*)d_in[1];  // [4096,4096]
    const float* mask   = (const float*)d_in[2];  // [4096,4096]
    const float* bias   = (const float*)d_in[3];  // [4096]
    float* out = (float*)d_out;

    short* dataB = (short*)d_ws;                  // 64 MB bf16 data
    short* wB    = dataB + (size_t)GM * GK;       // 32 MB bf16 masked weight

    cvt_data_kernel<<<2048, 256, 0, stream>>>(data, dataB, (long)GM * GK);
    cvt_w_kernel<<<2048, 256, 0, stream>>>(weight, mask, wB, (long)GN * GK);

    // grid = (8192/256) * (4096/256) = 32 * 16 = 512 workgroups, 8 waves each
    gemm_8w<<<512, 512, 0, stream>>>(dataB, wB, bias, out);
}